// Round 4
// baseline (325.151 us; speedup 1.0000x reference)
//
#include <hip/hip_runtime.h>
#include <math.h>
#include <stdint.h>

// ---------------------------------------------------------------------------
// Mlp_8744553415182 on MI355X (gfx950). FP32 I/O; bf16 MFMA compute.
//   1. prep_kernel:  x->xb(+xpad,s_x), W1->w1b(+w1pad,s_w), W2->w2b, b1->s_b
//   2. topk_gemm:    counts[n] += #(x_topk . w1_topk + b1 > 0)   (MFMA K=128)
//   3. gemm1_gelu:   h = gelu(x . W1^T + b1) bf16, ALL channels  (MFMA K=1024)
//   4. fixup_kernel: channels with counts<=2048 -> exact quantized path
//   5. gemm2_bias:   out = h . W2^T + b2, FP32 out               (MFMA K=4096)
// R3->R4: BK=32 -> BK=64 (32 KB LDS, 32 MFMA per barrier pair — AITER cadence;
// R3 counters: MfmaUtil 28 + VALUBusy 27 -> ~45% barrier-drain stall).
// LDS XOR-swizzle kept verbatim (R3: bank conflicts 8.4M -> 0).
// ---------------------------------------------------------------------------

typedef __bf16 v8bf __attribute__((ext_vector_type(8)));
typedef float v4f __attribute__((ext_vector_type(4)));

#define AS_G __attribute__((address_space(1)))
#define AS_L __attribute__((address_space(3)))

__device__ __forceinline__ unsigned short f2bf(float f) {
    union { float f; unsigned int i; } v; v.f = f;
    unsigned int r = v.i + 0x7fffu + ((v.i >> 16) & 1u);   // RNE
    return (unsigned short)(r >> 16);
}
__device__ __forceinline__ float gelu_fast(float v) {
    float u = v * (0.79788456080286536f + 0.035677408136300125f * v * v);
    u = fminf(fmaxf(u, -15.f), 15.f);
    float e = __expf(2.0f * u);
    return v * e * __builtin_amdgcn_rcpf(e + 1.0f);   // v*e/(e+1) = 0.5v(1+tanh u)
}
__device__ __forceinline__ float gelu_exact(float v) {
    return 0.5f * v * (1.0f + erff(v * 0.70710678118654752440f));
}

// --------------------------- MFMA GEMM core (BK=64) -------------------------
// 128x128 tile, BK=64, 256 threads (4 waves 2x2), 16x16x32 bf16 MFMA.
// A [M,K], B [N,K] row-major bf16. 32 KB LDS in four 8 KB regions
// (A-klo, A-khi, B-klo, B-khi), each the R3-verified swizzled layout:
// 16B-chunk l of a 1KB block holds (row=l>>2, colblk=(l&3)^((l>>3)&3));
// reader offset roff = R*32 + (Q^((R>>1)&3))*8  -> conflict-free b128 reads.
__device__ __forceinline__ void gemm_core64(const unsigned short* __restrict__ A,
                                            const unsigned short* __restrict__ B,
                                            int K, int bm0, int bn0,
                                            unsigned short* lds,   // 16384 ushorts
                                            v4f acc[4][4])
{
    const int tid  = threadIdx.x;
    const int wave = tid >> 6;
    const int lane = tid & 63;
    const int rowInChunk = lane >> 2;                         // 0..15
    const int col8 = ((lane & 3) ^ ((lane >> 3) & 3)) * 8;    // swizzled K-subblock
    const int ldsLane = lane * 8;
    const int c0 = wave * 2, c1 = wave * 2 + 1;
    const int wm = wave & 1, wn = wave >> 1;

    unsigned short* ldsA0 = lds;
    unsigned short* ldsA1 = lds + 4096;
    unsigned short* ldsB0 = lds + 8192;
    unsigned short* ldsB1 = lds + 12288;

    const size_t aR0 = (size_t)(bm0 + c0 * 16 + rowInChunk) * K + col8;
    const size_t aR1 = (size_t)(bm0 + c1 * 16 + rowInChunk) * K + col8;
    const size_t bR0 = (size_t)(bn0 + c0 * 16 + rowInChunk) * K + col8;
    const size_t bR1 = (size_t)(bn0 + c1 * 16 + rowInChunk) * K + col8;

    const int R = lane & 15, Q = lane >> 4;
    const int roff = R * 32 + ((Q ^ ((R >> 1) & 3)) * 8);

    for (int k0 = 0; k0 < K; k0 += 64) {
        __builtin_amdgcn_global_load_lds((const AS_G void*)(A + aR0 + k0),
                                         (AS_L void*)(ldsA0 + c0 * 512 + ldsLane), 16, 0, 0);
        __builtin_amdgcn_global_load_lds((const AS_G void*)(A + aR1 + k0),
                                         (AS_L void*)(ldsA0 + c1 * 512 + ldsLane), 16, 0, 0);
        __builtin_amdgcn_global_load_lds((const AS_G void*)(A + aR0 + k0 + 32),
                                         (AS_L void*)(ldsA1 + c0 * 512 + ldsLane), 16, 0, 0);
        __builtin_amdgcn_global_load_lds((const AS_G void*)(A + aR1 + k0 + 32),
                                         (AS_L void*)(ldsA1 + c1 * 512 + ldsLane), 16, 0, 0);
        __builtin_amdgcn_global_load_lds((const AS_G void*)(B + bR0 + k0),
                                         (AS_L void*)(ldsB0 + c0 * 512 + ldsLane), 16, 0, 0);
        __builtin_amdgcn_global_load_lds((const AS_G void*)(B + bR1 + k0),
                                         (AS_L void*)(ldsB0 + c1 * 512 + ldsLane), 16, 0, 0);
        __builtin_amdgcn_global_load_lds((const AS_G void*)(B + bR0 + k0 + 32),
                                         (AS_L void*)(ldsB1 + c0 * 512 + ldsLane), 16, 0, 0);
        __builtin_amdgcn_global_load_lds((const AS_G void*)(B + bR1 + k0 + 32),
                                         (AS_L void*)(ldsB1 + c1 * 512 + ldsLane), 16, 0, 0);
        __syncthreads();

        v8bf af0[4], bf0[4];
#pragma unroll
        for (int i = 0; i < 4; ++i)
            af0[i] = *(const v8bf*)&ldsA0[(wm * 4 + i) * 512 + roff];
#pragma unroll
        for (int j = 0; j < 4; ++j)
            bf0[j] = *(const v8bf*)&ldsB0[(wn * 4 + j) * 512 + roff];
#pragma unroll
        for (int i = 0; i < 4; ++i)
#pragma unroll
            for (int j = 0; j < 4; ++j)
                acc[i][j] = __builtin_amdgcn_mfma_f32_16x16x32_bf16(af0[i], bf0[j], acc[i][j], 0, 0, 0);

        v8bf af1[4], bf1[4];
#pragma unroll
        for (int i = 0; i < 4; ++i)
            af1[i] = *(const v8bf*)&ldsA1[(wm * 4 + i) * 512 + roff];
#pragma unroll
        for (int j = 0; j < 4; ++j)
            bf1[j] = *(const v8bf*)&ldsB1[(wn * 4 + j) * 512 + roff];
#pragma unroll
        for (int i = 0; i < 4; ++i)
#pragma unroll
            for (int j = 0; j < 4; ++j)
                acc[i][j] = __builtin_amdgcn_mfma_f32_16x16x32_bf16(af1[i], bf1[j], acc[i][j], 0, 0, 0);
        __syncthreads();
    }
}

// --------------------------- prep (fused) -----------------------------------
__global__ void prep_kernel(const float* __restrict__ x, const float* __restrict__ W1,
                            const float* __restrict__ W2, const float* __restrict__ b1,
                            unsigned short* __restrict__ xb, unsigned short* __restrict__ w1b,
                            unsigned short* __restrict__ w2b,
                            unsigned short* __restrict__ xpad, unsigned short* __restrict__ w1pad,
                            float* __restrict__ s_x, float* __restrict__ s_w,
                            float* __restrict__ s_b, int* __restrict__ counts)
{
    const int b = blockIdx.x, t = threadIdx.x;
    __shared__ float red[4];

    if (b < 16384) {
        const float* src; unsigned short* dst; unsigned short* pad = nullptr; float* sc = nullptr;
        if (b < 8192)       { src = x  + (size_t)b * 1024;            dst = xb  + (size_t)b * 1024;
                              pad = xpad  + (size_t)b * 128;          sc = s_x + b; }
        else if (b < 12288) { int r = b - 8192;  src = W1 + (size_t)r * 1024; dst = w1b + (size_t)r * 1024;
                              pad = w1pad + (size_t)r * 128;          sc = s_w + r; }
        else                { int r = b - 12288; src = W2 + (size_t)r * 1024; dst = w2b + (size_t)r * 1024; }

        float4 v = ((const float4*)src)[t];
        ushort4 u;
        u.x = f2bf(v.x); u.y = f2bf(v.y); u.z = f2bf(v.z); u.w = f2bf(v.w);
        ((ushort4*)dst)[t] = u;
        if (pad && t < 32) {
            int c = t * 4;
            ushort4 p;
            p.x = (c + 0 < 103) ? u.x : (unsigned short)0;
            p.y = (c + 1 < 103) ? u.y : (unsigned short)0;
            p.z = (c + 2 < 103) ? u.z : (unsigned short)0;
            p.w = (c + 3 < 103) ? u.w : (unsigned short)0;
            ((ushort4*)pad)[t] = p;
        }
        if (sc) {
            float m = fmaxf(fmaxf(fabsf(v.x), fabsf(v.y)), fmaxf(fabsf(v.z), fabsf(v.w)));
#pragma unroll
            for (int off = 32; off; off >>= 1) m = fmaxf(m, __shfl_xor(m, off, 64));
            if ((t & 63) == 0) red[t >> 6] = m;
            __syncthreads();
            if (t == 0) {
                m = fmaxf(fmaxf(red[0], red[1]), fmaxf(red[2], red[3]));
                *sc = fmaxf(m, 1e-5f) * (1.0f / 127.0f);
            }
        }
    } else {
        float m = 0.f;
        for (int k = t; k < 4096; k += 256) { m = fmaxf(m, fabsf(b1[k])); counts[k] = 0; }
#pragma unroll
        for (int off = 32; off; off >>= 1) m = fmaxf(m, __shfl_xor(m, off, 64));
        if ((t & 63) == 0) red[t >> 6] = m;
        __syncthreads();
        if (t == 0) {
            m = fmaxf(fmaxf(red[0], red[1]), fmaxf(red[2], red[3]));
            *s_b = fmaxf(m, 1e-5f) * (1.0f / 127.0f);
        }
    }
}

// --------------------------- topk counts ------------------------------------
__global__ void topk_gemm(const unsigned short* __restrict__ xpad,
                          const unsigned short* __restrict__ w1pad,
                          const float* __restrict__ b1,
                          int* __restrict__ counts)
{
    __shared__ unsigned short lds[16384];
    v4f acc[4][4];
    v4f z = {0.f, 0.f, 0.f, 0.f};
#pragma unroll
    for (int i = 0; i < 4; ++i)
#pragma unroll
        for (int j = 0; j < 4; ++j) acc[i][j] = z;

    const int bm0 = blockIdx.x * 128, bn0 = blockIdx.y * 128;
    gemm_core64(xpad, w1pad, 128, bm0, bn0, lds, acc);

    const int lane = threadIdx.x & 63, wave = threadIdx.x >> 6;
    const int wn = wave >> 1;
#pragma unroll
    for (int j = 0; j < 4; ++j) {
        int n = bn0 + wn * 64 + j * 16 + (lane & 15);
        float bv = b1[n];
        int cnt = 0;
#pragma unroll
        for (int i = 0; i < 4; ++i)
#pragma unroll
            for (int r = 0; r < 4; ++r)
                cnt += (acc[i][j][r] + bv > 0.0f) ? 1 : 0;
        cnt += __shfl_xor(cnt, 16, 64);
        cnt += __shfl_xor(cnt, 32, 64);
        if (lane < 16 && cnt) atomicAdd(&counts[n], cnt);
    }
}

// --------------------------- gemm1 + gelu ------------------------------------
__global__ void gemm1_gelu(const unsigned short* __restrict__ xb,
                           const unsigned short* __restrict__ w1b,
                           const float* __restrict__ b1,
                           unsigned short* __restrict__ hbuf)
{
    __shared__ unsigned short lds[16384];
    v4f acc[4][4];
    v4f z = {0.f, 0.f, 0.f, 0.f};
#pragma unroll
    for (int i = 0; i < 4; ++i)
#pragma unroll
        for (int j = 0; j < 4; ++j) acc[i][j] = z;

    const int bm0 = blockIdx.x * 128, bn0 = blockIdx.y * 128;
    gemm_core64(xb, w1b, 1024, bm0, bn0, lds, acc);

    const int lane = threadIdx.x & 63, wave = threadIdx.x >> 6;
    const int wm = wave & 1, wn = wave >> 1;
#pragma unroll
    for (int j = 0; j < 4; ++j) {
        int n = bn0 + wn * 64 + j * 16 + (lane & 15);
        float bv = b1[n];
#pragma unroll
        for (int i = 0; i < 4; ++i)
#pragma unroll
            for (int r = 0; r < 4; ++r) {
                int m = bm0 + wm * 64 + i * 16 + (lane >> 4) * 4 + r;
                hbuf[(size_t)m * 4096 + n] = f2bf(gelu_fast(acc[i][j][r] + bv));
            }
    }
}

// --------------------------- fixup (exact quant path) ------------------------
__global__ void fixup_kernel(const float* __restrict__ x,
                             const float* __restrict__ W1,
                             const float* __restrict__ b1,
                             const int* __restrict__ counts,
                             const float* __restrict__ s_x,
                             const float* __restrict__ s_w,
                             const float* __restrict__ s_b,
                             unsigned short* __restrict__ hbuf)
{
    const int n = blockIdx.x;
    if (counts[n] > 2048) return;   // fp channel: keep gemm1 result
    __shared__ float qw[1024];
    const float swn = s_w[n];
    for (int k = threadIdx.x; k < 1024; k += 256) {
        float q = nearbyintf(W1[(size_t)n * 1024 + k] / swn);
        qw[k] = fminf(fmaxf(q, -128.f), 127.f) * swn;
    }
    __syncthreads();
    const float sb = *s_b;
    const float bq = fminf(fmaxf(nearbyintf(b1[n] / sb), -128.f), 127.f) * sb;
    for (int m = threadIdx.x; m < 8192; m += 256) {
        const float sxm = s_x[m];
        float a = 0.f;
        for (int k = 0; k < 1024; ++k) {
            float q = nearbyintf(x[(size_t)m * 1024 + k] / sxm);
            a += fminf(fmaxf(q, -128.f), 127.f) * sxm * qw[k];
        }
        hbuf[(size_t)m * 4096 + n] = f2bf(gelu_exact(a + bq));
    }
}

// --------------------------- gemm2 + bias ------------------------------------
__global__ void gemm2_bias(const unsigned short* __restrict__ hbuf,
                           const unsigned short* __restrict__ w2b,
                           const float* __restrict__ b2,
                           float* __restrict__ out)
{
    __shared__ unsigned short lds[16384];
    v4f acc[4][4];
    v4f z = {0.f, 0.f, 0.f, 0.f};
#pragma unroll
    for (int i = 0; i < 4; ++i)
#pragma unroll
        for (int j = 0; j < 4; ++j) acc[i][j] = z;

    const int bm0 = blockIdx.x * 128, bn0 = blockIdx.y * 128;
    gemm_core64(hbuf, w2b, 4096, bm0, bn0, lds, acc);

    const int lane = threadIdx.x & 63, wave = threadIdx.x >> 6;
    const int wm = wave & 1, wn = wave >> 1;
#pragma unroll
    for (int j = 0; j < 4; ++j) {
        int n = bn0 + wn * 64 + j * 16 + (lane & 15);
        float bv = b2[n];
#pragma unroll
        for (int i = 0; i < 4; ++i)
#pragma unroll
            for (int r = 0; r < 4; ++r) {
                int m = bm0 + wm * 64 + i * 16 + (lane >> 4) * 4 + r;
                out[(size_t)m * 1024 + n] = acc[i][j][r] + bv;
            }
    }
}

// --------------------------- launch ----------------------------------------
extern "C" void kernel_launch(void* const* d_in, const int* in_sizes, int n_in,
                              void* d_out, int out_size, void* d_ws, size_t ws_size,
                              hipStream_t stream)
{
    const float* x  = (const float*)d_in[0];   // [4,2048,1024] fp32
    const float* W1 = (const float*)d_in[1];   // [4096,1024]
    const float* b1 = (const float*)d_in[2];   // [4096]
    const float* W2 = (const float*)d_in[3];   // [1024,4096]
    const float* b2 = (const float*)d_in[4];   // [1024]
    float* out = (float*)d_out;                // [4,2048,1024] fp32 (32 MB)

    // bf16 copies of x and W1 parked in d_out (dead until gemm2 writes it):
    unsigned short* xb  = (unsigned short*)d_out;                       // 16 MB
    unsigned short* w1b = (unsigned short*)d_out + (size_t)8192 * 1024; // 8 MB

    char* ws = (char*)d_ws;
    int*   counts = (int*)(ws + 0);                       // 16 KB
    float* s_x    = (float*)(ws + (64 << 10));            // 32 KB
    float* s_w    = (float*)(ws + (96 << 10));            // 16 KB
    float* s_b    = (float*)(ws + (112 << 10));           // 4 B
    unsigned short* xpad  = (unsigned short*)(ws + (1 << 20));   // 2 MB
    unsigned short* w1pad = (unsigned short*)(ws + (3 << 20));   // 1 MB
    unsigned short* w2b   = (unsigned short*)(ws + (4 << 20));   // 8 MB
    unsigned short* hbuf  = (unsigned short*)(ws + (12 << 20));  // 64 MB -> 76 MB total

    prep_kernel<<<16385, 256, 0, stream>>>(x, W1, W2, b1, xb, w1b, w2b,
                                           xpad, w1pad, s_x, s_w, s_b, counts);
    topk_gemm<<<dim3(64, 32), 256, 0, stream>>>(xpad, w1pad, b1, counts);
    gemm1_gelu<<<dim3(64, 32), 256, 0, stream>>>(xb, w1b, b1, hbuf);
    fixup_kernel<<<4096, 256, 0, stream>>>(x, W1, b1, counts, s_x, s_w, s_b, hbuf);
    gemm2_bias<<<dim3(64, 8), 256, 0, stream>>>(hbuf, w2b, b2, out);
}

// Round 5
// 307.844 us; speedup vs baseline: 1.0562x; 1.0562x over previous
//
#include <hip/hip_runtime.h>
#include <math.h>
#include <stdint.h>

// ---------------------------------------------------------------------------
// Mlp_8744553415182 on MI355X (gfx950). FP32 I/O; bf16 MFMA compute.
//   1. prep_kernel:  x->xb(+xpad,s_x), W1->w1b(+w1pad,s_w), W2->w2b, b1->s_b
//   2. topk_gemm:    counts[n] += #(x_topk . w1_topk + b1 > 0)   (MFMA K=128)
//   3. gemm1_gelu:   h = gelu(x . W1^T + b1) bf16, ALL channels  (MFMA K=1024)
//   4. fixup_kernel: channels with counts<=2048 -> exact quantized path
//   5. gemm2_bias:   out = h . W2^T + b2, FP32 out               (MFMA K=4096)
// R4->R5: BK=64 REVERTED (R4: occupancy 36->22, MfmaUtil 28->22 — LDS-driven
// occupancy loss beat barrier amortization; m132 pattern). Back to BK=32 core
// (R3-verified: 0 bank conflicts). NEW: coalesced epilogues via 16 KB LDS
// slab transpose (R3 counters: gemm1 WRITE 109 MB vs 64 ideal, gemm2 48 vs 32).
// ---------------------------------------------------------------------------

typedef __bf16 v8bf __attribute__((ext_vector_type(8)));
typedef float v4f __attribute__((ext_vector_type(4)));
typedef unsigned short v8us __attribute__((ext_vector_type(8)));

#define AS_G __attribute__((address_space(1)))
#define AS_L __attribute__((address_space(3)))

__device__ __forceinline__ unsigned short f2bf(float f) {
    union { float f; unsigned int i; } v; v.f = f;
    unsigned int r = v.i + 0x7fffu + ((v.i >> 16) & 1u);   // RNE
    return (unsigned short)(r >> 16);
}
__device__ __forceinline__ float gelu_fast(float v) {
    float u = v * (0.79788456080286536f + 0.035677408136300125f * v * v);
    u = fminf(fmaxf(u, -15.f), 15.f);
    float e = __expf(2.0f * u);
    return v * e * __builtin_amdgcn_rcpf(e + 1.0f);   // v*e/(e+1) = 0.5v(1+tanh u)
}
__device__ __forceinline__ float gelu_exact(float v) {
    return 0.5f * v * (1.0f + erff(v * 0.70710678118654752440f));
}

// --------------------------- MFMA GEMM core (BK=32) -------------------------
// 128x128 tile, BK=32, 256 threads (4 waves 2x2), 16x16x32 bf16 MFMA.
// lds: 8192 ushorts = 16 KB; A region = lds[0:4096], B = lds[4096:8192].
// XOR swizzle (R3-verified conflict-free): 16B-chunk l of each 1KB block holds
// (row=l>>2, colblk=(l&3)^((l>>3)&3)); reader roff = R*32 + (Q^((R>>1)&3))*8.
__device__ __forceinline__ void gemm_core(const unsigned short* __restrict__ A,
                                          const unsigned short* __restrict__ B,
                                          int K, int bm0, int bn0,
                                          unsigned short* lds,
                                          v4f acc[4][4])
{
    const int tid  = threadIdx.x;
    const int wave = tid >> 6;
    const int lane = tid & 63;
    const int rowInChunk = lane >> 2;                         // 0..15
    const int col8 = ((lane & 3) ^ ((lane >> 3) & 3)) * 8;    // swizzled K-block
    const int ldsLane = lane * 8;
    const int c0 = wave * 2, c1 = wave * 2 + 1;
    const int wm = wave & 1, wn = wave >> 1;

    unsigned short* ldsA = lds;
    unsigned short* ldsB = lds + 4096;

    const size_t aR0 = (size_t)(bm0 + c0 * 16 + rowInChunk) * K + col8;
    const size_t aR1 = (size_t)(bm0 + c1 * 16 + rowInChunk) * K + col8;
    const size_t bR0 = (size_t)(bn0 + c0 * 16 + rowInChunk) * K + col8;
    const size_t bR1 = (size_t)(bn0 + c1 * 16 + rowInChunk) * K + col8;

    const int R = lane & 15, Q = lane >> 4;
    const int roff = R * 32 + ((Q ^ ((R >> 1) & 3)) * 8);

    for (int k0 = 0; k0 < K; k0 += 32) {
        __builtin_amdgcn_global_load_lds((const AS_G void*)(A + aR0 + k0),
                                         (AS_L void*)(ldsA + c0 * 512 + ldsLane), 16, 0, 0);
        __builtin_amdgcn_global_load_lds((const AS_G void*)(A + aR1 + k0),
                                         (AS_L void*)(ldsA + c1 * 512 + ldsLane), 16, 0, 0);
        __builtin_amdgcn_global_load_lds((const AS_G void*)(B + bR0 + k0),
                                         (AS_L void*)(ldsB + c0 * 512 + ldsLane), 16, 0, 0);
        __builtin_amdgcn_global_load_lds((const AS_G void*)(B + bR1 + k0),
                                         (AS_L void*)(ldsB + c1 * 512 + ldsLane), 16, 0, 0);
        __syncthreads();

        v8bf af[4], bfr[4];
#pragma unroll
        for (int i = 0; i < 4; ++i)
            af[i] = *(const v8bf*)&ldsA[(wm * 4 + i) * 512 + roff];
#pragma unroll
        for (int j = 0; j < 4; ++j)
            bfr[j] = *(const v8bf*)&ldsB[(wn * 4 + j) * 512 + roff];
#pragma unroll
        for (int i = 0; i < 4; ++i)
#pragma unroll
            for (int j = 0; j < 4; ++j)
                acc[i][j] = __builtin_amdgcn_mfma_f32_16x16x32_bf16(af[i], bfr[j], acc[i][j], 0, 0, 0);
        __syncthreads();
    }
}

// --------------------------- prep (fused) -----------------------------------
__global__ void prep_kernel(const float* __restrict__ x, const float* __restrict__ W1,
                            const float* __restrict__ W2, const float* __restrict__ b1,
                            unsigned short* __restrict__ xb, unsigned short* __restrict__ w1b,
                            unsigned short* __restrict__ w2b,
                            unsigned short* __restrict__ xpad, unsigned short* __restrict__ w1pad,
                            float* __restrict__ s_x, float* __restrict__ s_w,
                            float* __restrict__ s_b, int* __restrict__ counts)
{
    const int b = blockIdx.x, t = threadIdx.x;
    __shared__ float red[4];

    if (b < 16384) {
        const float* src; unsigned short* dst; unsigned short* pad = nullptr; float* sc = nullptr;
        if (b < 8192)       { src = x  + (size_t)b * 1024;            dst = xb  + (size_t)b * 1024;
                              pad = xpad  + (size_t)b * 128;          sc = s_x + b; }
        else if (b < 12288) { int r = b - 8192;  src = W1 + (size_t)r * 1024; dst = w1b + (size_t)r * 1024;
                              pad = w1pad + (size_t)r * 128;          sc = s_w + r; }
        else                { int r = b - 12288; src = W2 + (size_t)r * 1024; dst = w2b + (size_t)r * 1024; }

        float4 v = ((const float4*)src)[t];
        ushort4 u;
        u.x = f2bf(v.x); u.y = f2bf(v.y); u.z = f2bf(v.z); u.w = f2bf(v.w);
        ((ushort4*)dst)[t] = u;
        if (pad && t < 32) {
            int c = t * 4;
            ushort4 p;
            p.x = (c + 0 < 103) ? u.x : (unsigned short)0;
            p.y = (c + 1 < 103) ? u.y : (unsigned short)0;
            p.z = (c + 2 < 103) ? u.z : (unsigned short)0;
            p.w = (c + 3 < 103) ? u.w : (unsigned short)0;
            ((ushort4*)pad)[t] = p;
        }
        if (sc) {
            float m = fmaxf(fmaxf(fabsf(v.x), fabsf(v.y)), fmaxf(fabsf(v.z), fabsf(v.w)));
#pragma unroll
            for (int off = 32; off; off >>= 1) m = fmaxf(m, __shfl_xor(m, off, 64));
            if ((t & 63) == 0) red[t >> 6] = m;
            __syncthreads();
            if (t == 0) {
                m = fmaxf(fmaxf(red[0], red[1]), fmaxf(red[2], red[3]));
                *sc = fmaxf(m, 1e-5f) * (1.0f / 127.0f);
            }
        }
    } else {
        float m = 0.f;
        for (int k = t; k < 4096; k += 256) { m = fmaxf(m, fabsf(b1[k])); counts[k] = 0; }
#pragma unroll
        for (int off = 32; off; off >>= 1) m = fmaxf(m, __shfl_xor(m, off, 64));
        if ((t & 63) == 0) red[t >> 6] = m;
        __syncthreads();
        if (t == 0) {
            m = fmaxf(fmaxf(red[0], red[1]), fmaxf(red[2], red[3]));
            *s_b = fmaxf(m, 1e-5f) * (1.0f / 127.0f);
        }
    }
}

// --------------------------- topk counts ------------------------------------
__global__ void topk_gemm(const unsigned short* __restrict__ xpad,
                          const unsigned short* __restrict__ w1pad,
                          const float* __restrict__ b1,
                          int* __restrict__ counts)
{
    __shared__ unsigned short lds[8192];
    v4f acc[4][4];
    v4f z = {0.f, 0.f, 0.f, 0.f};
#pragma unroll
    for (int i = 0; i < 4; ++i)
#pragma unroll
        for (int j = 0; j < 4; ++j) acc[i][j] = z;

    const int bm0 = blockIdx.x * 128, bn0 = blockIdx.y * 128;
    gemm_core(xpad, w1pad, 128, bm0, bn0, lds, acc);

    const int lane = threadIdx.x & 63, wave = threadIdx.x >> 6;
    const int wn = wave >> 1;
#pragma unroll
    for (int j = 0; j < 4; ++j) {
        int n = bn0 + wn * 64 + j * 16 + (lane & 15);
        float bv = b1[n];
        int cnt = 0;
#pragma unroll
        for (int i = 0; i < 4; ++i)
#pragma unroll
            for (int r = 0; r < 4; ++r)
                cnt += (acc[i][j][r] + bv > 0.0f) ? 1 : 0;
        cnt += __shfl_xor(cnt, 16, 64);
        cnt += __shfl_xor(cnt, 32, 64);
        if (lane < 16 && cnt) atomicAdd(&counts[n], cnt);
    }
}

// --------------------------- gemm1 + gelu ------------------------------------
// Epilogue: 2 passes of a 64x128 bf16 LDS slab (16 KB), coalesced ushort8 out.
__global__ void gemm1_gelu(const unsigned short* __restrict__ xb,
                           const unsigned short* __restrict__ w1b,
                           const float* __restrict__ b1,
                           unsigned short* __restrict__ hbuf)
{
    __shared__ unsigned short lds[8192];
    v4f acc[4][4];
    v4f z = {0.f, 0.f, 0.f, 0.f};
#pragma unroll
    for (int i = 0; i < 4; ++i)
#pragma unroll
        for (int j = 0; j < 4; ++j) acc[i][j] = z;

    const int bm0 = blockIdx.x * 128, bn0 = blockIdx.y * 128;
    gemm_core(xb, w1b, 1024, bm0, bn0, lds, acc);

    const int tid = threadIdx.x;
    const int lane = tid & 63, wave = tid >> 6;
    const int wm = wave & 1, wn = wave >> 1, q = lane >> 4;

    float bvj[4];
#pragma unroll
    for (int j = 0; j < 4; ++j) bvj[j] = b1[bn0 + wn * 64 + j * 16 + (lane & 15)];

#pragma unroll
    for (int p = 0; p < 2; ++p) {
        __syncthreads();
        if (wm == p) {
#pragma unroll
            for (int j = 0; j < 4; ++j) {
                int nl = wn * 64 + j * 16 + (lane & 15);
#pragma unroll
                for (int i = 0; i < 4; ++i)
#pragma unroll
                    for (int r = 0; r < 4; ++r)
                        lds[(i * 16 + q * 4 + r) * 128 + nl] =
                            f2bf(gelu_fast(acc[i][j][r] + bvj[j]));
            }
        }
        __syncthreads();
#pragma unroll
        for (int s = 0; s < 4; ++s) {
            int c = s * 256 + tid;           // 0..1023
            int row = c >> 4, ch = c & 15;   // 64 rows x 16 chunks of 16B
            *(v8us*)&hbuf[(size_t)(bm0 + p * 64 + row) * 4096 + bn0 + ch * 8] =
                *(const v8us*)&lds[row * 128 + ch * 8];
        }
    }
}

// --------------------------- fixup (exact quant path) ------------------------
__global__ void fixup_kernel(const float* __restrict__ x,
                             const float* __restrict__ W1,
                             const float* __restrict__ b1,
                             const int* __restrict__ counts,
                             const float* __restrict__ s_x,
                             const float* __restrict__ s_w,
                             const float* __restrict__ s_b,
                             unsigned short* __restrict__ hbuf)
{
    const int n = blockIdx.x;
    if (counts[n] > 2048) return;   // fp channel: keep gemm1 result
    __shared__ float qw[1024];
    const float swn = s_w[n];
    for (int k = threadIdx.x; k < 1024; k += 256) {
        float q = nearbyintf(W1[(size_t)n * 1024 + k] / swn);
        qw[k] = fminf(fmaxf(q, -128.f), 127.f) * swn;
    }
    __syncthreads();
    const float sb = *s_b;
    const float bq = fminf(fmaxf(nearbyintf(b1[n] / sb), -128.f), 127.f) * sb;
    for (int m = threadIdx.x; m < 8192; m += 256) {
        const float sxm = s_x[m];
        float a = 0.f;
        for (int k = 0; k < 1024; ++k) {
            float q = nearbyintf(x[(size_t)m * 1024 + k] / sxm);
            a += fminf(fmaxf(q, -128.f), 127.f) * sxm * qw[k];
        }
        hbuf[(size_t)m * 4096 + n] = f2bf(gelu_exact(a + bq));
    }
}

// --------------------------- gemm2 + bias ------------------------------------
// Epilogue: 4 passes of a 32x128 fp32 LDS slab (16 KB), coalesced float4 out.
__global__ void gemm2_bias(const unsigned short* __restrict__ hbuf,
                           const unsigned short* __restrict__ w2b,
                           const float* __restrict__ b2,
                           float* __restrict__ out)
{
    __shared__ unsigned short lds[8192];
    v4f acc[4][4];
    v4f z = {0.f, 0.f, 0.f, 0.f};
#pragma unroll
    for (int i = 0; i < 4; ++i)
#pragma unroll
        for (int j = 0; j < 4; ++j) acc[i][j] = z;

    const int bm0 = blockIdx.x * 128, bn0 = blockIdx.y * 128;
    gemm_core(hbuf, w2b, 4096, bm0, bn0, lds, acc);

    const int tid = threadIdx.x;
    const int lane = tid & 63, wave = tid >> 6;
    const int wm = wave & 1, wn = wave >> 1, q = lane >> 4;
    float* ldsf = (float*)lds;               // 4096 floats = 16 KB

    float bvj[4];
#pragma unroll
    for (int j = 0; j < 4; ++j) bvj[j] = b2[bn0 + wn * 64 + j * 16 + (lane & 15)];

#pragma unroll
    for (int p = 0; p < 4; ++p) {
        __syncthreads();
        if (wm == (p >> 1)) {
            const int ibase = (p & 1) * 2;
#pragma unroll
            for (int ii = 0; ii < 2; ++ii) {
#pragma unroll
                for (int j = 0; j < 4; ++j) {
                    int nl = wn * 64 + j * 16 + (lane & 15);
#pragma unroll
                    for (int r = 0; r < 4; ++r)
                        ldsf[(ii * 16 + q * 4 + r) * 128 + nl] =
                            acc[ibase + ii][j][r] + bvj[j];
                }
            }
        }
        __syncthreads();
#pragma unroll
        for (int s = 0; s < 4; ++s) {
            int c = s * 256 + tid;           // 0..1023
            int row = c >> 5, ch = c & 31;   // 32 rows x 32 chunks of 16B
            *(float4*)&out[(size_t)(bm0 + p * 32 + row) * 1024 + bn0 + ch * 4] =
                *(const float4*)&ldsf[row * 128 + ch * 4];
        }
    }
}

// --------------------------- launch ----------------------------------------
extern "C" void kernel_launch(void* const* d_in, const int* in_sizes, int n_in,
                              void* d_out, int out_size, void* d_ws, size_t ws_size,
                              hipStream_t stream)
{
    const float* x  = (const float*)d_in[0];   // [4,2048,1024] fp32
    const float* W1 = (const float*)d_in[1];   // [4096,1024]
    const float* b1 = (const float*)d_in[2];   // [4096]
    const float* W2 = (const float*)d_in[3];   // [1024,4096]
    const float* b2 = (const float*)d_in[4];   // [1024]
    float* out = (float*)d_out;                // [4,2048,1024] fp32 (32 MB)

    // bf16 copies of x and W1 parked in d_out (dead until gemm2 writes it):
    unsigned short* xb  = (unsigned short*)d_out;                       // 16 MB
    unsigned short* w1b = (unsigned short*)d_out + (size_t)8192 * 1024; // 8 MB

    char* ws = (char*)d_ws;
    int*   counts = (int*)(ws + 0);                       // 16 KB
    float* s_x    = (float*)(ws + (64 << 10));            // 32 KB
    float* s_w    = (float*)(ws + (96 << 10));            // 16 KB
    float* s_b    = (float*)(ws + (112 << 10));           // 4 B
    unsigned short* xpad  = (unsigned short*)(ws + (1 << 20));   // 2 MB
    unsigned short* w1pad = (unsigned short*)(ws + (3 << 20));   // 1 MB
    unsigned short* w2b   = (unsigned short*)(ws + (4 << 20));   // 8 MB
    unsigned short* hbuf  = (unsigned short*)(ws + (12 << 20));  // 64 MB -> 76 MB total

    prep_kernel<<<16385, 256, 0, stream>>>(x, W1, W2, b1, xb, w1b, w2b,
                                           xpad, w1pad, s_x, s_w, s_b, counts);
    topk_gemm<<<dim3(64, 32), 256, 0, stream>>>(xpad, w1pad, b1, counts);
    gemm1_gelu<<<dim3(64, 32), 256, 0, stream>>>(xb, w1b, b1, hbuf);
    fixup_kernel<<<4096, 256, 0, stream>>>(x, W1, b1, counts, s_x, s_w, s_b, hbuf);
    gemm2_bias<<<dim3(64, 8), 256, 0, stream>>>(hbuf, w2b, b2, out);
}

// Round 6
// 300.064 us; speedup vs baseline: 1.0836x; 1.0259x over previous
//
#include <hip/hip_runtime.h>
#include <math.h>
#include <stdint.h>

// ---------------------------------------------------------------------------
// Mlp_8744553415182 on MI355X (gfx950). FP32 I/O; bf16 MFMA compute.
//   1. prep_kernel:  x->xb(+xpad,s_x), W1->w1b(+w1pad,s_w), W2->w2b, s_b, counts=0
//   2. gemm1_topk:   z=0 blocks: h = gelu(x.W1^T+b1) (MFMA K=1024, slab epilogue)
//                    z=1 blocks: counts[n] += #(x_topk.w1_topk+b1 > 0) (K=128)
//                    (fused: topk only feeds fixup; overlapping hides its ~15us)
//   3. fixup_kernel: channels with counts<=2048 -> exact quantized path
//   4. gemm2_bias:   out = h.W2^T + b2, FP32 out (MFMA K=4096, 128x64 tile)
// R5->R6: gemm2 128x128 -> 128x64 tile (512 -> 1024 blocks; R4 showed gemm2
// block-limited at 2 blocks/CU = 22% occupancy). topk fused into gemm1 dispatch.
// BK=32 core + XOR swizzle (R3: 0 conflicts) + slab epilogues (R5: WRITE ideal).
// ---------------------------------------------------------------------------

typedef __bf16 v8bf __attribute__((ext_vector_type(8)));
typedef float v4f __attribute__((ext_vector_type(4)));
typedef unsigned short v8us __attribute__((ext_vector_type(8)));

#define AS_G __attribute__((address_space(1)))
#define AS_L __attribute__((address_space(3)))

__device__ __forceinline__ unsigned short f2bf(float f) {
    union { float f; unsigned int i; } v; v.f = f;
    unsigned int r = v.i + 0x7fffu + ((v.i >> 16) & 1u);   // RNE
    return (unsigned short)(r >> 16);
}
__device__ __forceinline__ float gelu_fast(float v) {
    float u = v * (0.79788456080286536f + 0.035677408136300125f * v * v);
    u = fminf(fmaxf(u, -15.f), 15.f);
    float e = __expf(2.0f * u);
    return v * e * __builtin_amdgcn_rcpf(e + 1.0f);   // v*e/(e+1) = 0.5v(1+tanh u)
}
__device__ __forceinline__ float gelu_exact(float v) {
    return 0.5f * v * (1.0f + erff(v * 0.70710678118654752440f));
}

// --------------------------- MFMA GEMM core (BK=32, 128xN tile) -------------
// 128x128: 4 waves 2x2, acc[4][4].  XOR swizzle (R3-verified conflict-free):
// 16B-chunk l of each 1KB block holds (row=l>>2, colblk=(l&3)^((l>>3)&3));
// reader roff = R*32 + (Q^((R>>1)&3))*8.
__device__ __forceinline__ void gemm_core(const unsigned short* __restrict__ A,
                                          const unsigned short* __restrict__ B,
                                          int K, int bm0, int bn0,
                                          unsigned short* lds,
                                          v4f acc[4][4])
{
    const int tid  = threadIdx.x;
    const int wave = tid >> 6;
    const int lane = tid & 63;
    const int rowInChunk = lane >> 2;
    const int col8 = ((lane & 3) ^ ((lane >> 3) & 3)) * 8;
    const int ldsLane = lane * 8;
    const int c0 = wave * 2, c1 = wave * 2 + 1;
    const int wm = wave & 1, wn = wave >> 1;

    unsigned short* ldsA = lds;
    unsigned short* ldsB = lds + 4096;

    const size_t aR0 = (size_t)(bm0 + c0 * 16 + rowInChunk) * K + col8;
    const size_t aR1 = (size_t)(bm0 + c1 * 16 + rowInChunk) * K + col8;
    const size_t bR0 = (size_t)(bn0 + c0 * 16 + rowInChunk) * K + col8;
    const size_t bR1 = (size_t)(bn0 + c1 * 16 + rowInChunk) * K + col8;

    const int R = lane & 15, Q = lane >> 4;
    const int roff = R * 32 + ((Q ^ ((R >> 1) & 3)) * 8);

    for (int k0 = 0; k0 < K; k0 += 32) {
        __builtin_amdgcn_global_load_lds((const AS_G void*)(A + aR0 + k0),
                                         (AS_L void*)(ldsA + c0 * 512 + ldsLane), 16, 0, 0);
        __builtin_amdgcn_global_load_lds((const AS_G void*)(A + aR1 + k0),
                                         (AS_L void*)(ldsA + c1 * 512 + ldsLane), 16, 0, 0);
        __builtin_amdgcn_global_load_lds((const AS_G void*)(B + bR0 + k0),
                                         (AS_L void*)(ldsB + c0 * 512 + ldsLane), 16, 0, 0);
        __builtin_amdgcn_global_load_lds((const AS_G void*)(B + bR1 + k0),
                                         (AS_L void*)(ldsB + c1 * 512 + ldsLane), 16, 0, 0);
        __syncthreads();

        v8bf af[4], bfr[4];
#pragma unroll
        for (int i = 0; i < 4; ++i)
            af[i] = *(const v8bf*)&ldsA[(wm * 4 + i) * 512 + roff];
#pragma unroll
        for (int j = 0; j < 4; ++j)
            bfr[j] = *(const v8bf*)&ldsB[(wn * 4 + j) * 512 + roff];
#pragma unroll
        for (int i = 0; i < 4; ++i)
#pragma unroll
            for (int j = 0; j < 4; ++j)
                acc[i][j] = __builtin_amdgcn_mfma_f32_16x16x32_bf16(af[i], bfr[j], acc[i][j], 0, 0, 0);
        __syncthreads();
    }
}

// 128x64 tile variant: 4 waves 2x2 over (128M, 64N), acc[4][2]. 12 KB LDS.
__device__ __forceinline__ void gemm_core64N(const unsigned short* __restrict__ A,
                                             const unsigned short* __restrict__ B,
                                             int K, int bm0, int bn0,
                                             unsigned short* lds,
                                             v4f acc[4][2])
{
    const int tid  = threadIdx.x;
    const int wave = tid >> 6;
    const int lane = tid & 63;
    const int rowInChunk = lane >> 2;
    const int col8 = ((lane & 3) ^ ((lane >> 3) & 3)) * 8;
    const int ldsLane = lane * 8;
    const int c0 = wave * 2, c1 = wave * 2 + 1;
    const int wm = wave & 1, wn = wave >> 1;

    unsigned short* ldsA = lds;            // 128x32 = 8 KB
    unsigned short* ldsB = lds + 4096;     // 64x32  = 4 KB

    const size_t aR0 = (size_t)(bm0 + c0 * 16 + rowInChunk) * K + col8;
    const size_t aR1 = (size_t)(bm0 + c1 * 16 + rowInChunk) * K + col8;
    const size_t bR  = (size_t)(bn0 + wave * 16 + rowInChunk) * K + col8;

    const int R = lane & 15, Q = lane >> 4;
    const int roff = R * 32 + ((Q ^ ((R >> 1) & 3)) * 8);

    for (int k0 = 0; k0 < K; k0 += 32) {
        __builtin_amdgcn_global_load_lds((const AS_G void*)(A + aR0 + k0),
                                         (AS_L void*)(ldsA + c0 * 512 + ldsLane), 16, 0, 0);
        __builtin_amdgcn_global_load_lds((const AS_G void*)(A + aR1 + k0),
                                         (AS_L void*)(ldsA + c1 * 512 + ldsLane), 16, 0, 0);
        __builtin_amdgcn_global_load_lds((const AS_G void*)(B + bR + k0),
                                         (AS_L void*)(ldsB + wave * 512 + ldsLane), 16, 0, 0);
        __syncthreads();

        v8bf af[4], bfr[2];
#pragma unroll
        for (int i = 0; i < 4; ++i)
            af[i] = *(const v8bf*)&ldsA[(wm * 4 + i) * 512 + roff];
#pragma unroll
        for (int j = 0; j < 2; ++j)
            bfr[j] = *(const v8bf*)&ldsB[(wn * 2 + j) * 512 + roff];
#pragma unroll
        for (int i = 0; i < 4; ++i)
#pragma unroll
            for (int j = 0; j < 2; ++j)
                acc[i][j] = __builtin_amdgcn_mfma_f32_16x16x32_bf16(af[i], bfr[j], acc[i][j], 0, 0, 0);
        __syncthreads();
    }
}

// --------------------------- prep (fused) -----------------------------------
__global__ void prep_kernel(const float* __restrict__ x, const float* __restrict__ W1,
                            const float* __restrict__ W2, const float* __restrict__ b1,
                            unsigned short* __restrict__ xb, unsigned short* __restrict__ w1b,
                            unsigned short* __restrict__ w2b,
                            unsigned short* __restrict__ xpad, unsigned short* __restrict__ w1pad,
                            float* __restrict__ s_x, float* __restrict__ s_w,
                            float* __restrict__ s_b, int* __restrict__ counts)
{
    const int b = blockIdx.x, t = threadIdx.x;
    __shared__ float red[4];

    if (b < 16384) {
        const float* src; unsigned short* dst; unsigned short* pad = nullptr; float* sc = nullptr;
        if (b < 8192)       { src = x  + (size_t)b * 1024;            dst = xb  + (size_t)b * 1024;
                              pad = xpad  + (size_t)b * 128;          sc = s_x + b; }
        else if (b < 12288) { int r = b - 8192;  src = W1 + (size_t)r * 1024; dst = w1b + (size_t)r * 1024;
                              pad = w1pad + (size_t)r * 128;          sc = s_w + r; }
        else                { int r = b - 12288; src = W2 + (size_t)r * 1024; dst = w2b + (size_t)r * 1024; }

        float4 v = ((const float4*)src)[t];
        ushort4 u;
        u.x = f2bf(v.x); u.y = f2bf(v.y); u.z = f2bf(v.z); u.w = f2bf(v.w);
        ((ushort4*)dst)[t] = u;
        if (pad && t < 32) {
            int c = t * 4;
            ushort4 p;
            p.x = (c + 0 < 103) ? u.x : (unsigned short)0;
            p.y = (c + 1 < 103) ? u.y : (unsigned short)0;
            p.z = (c + 2 < 103) ? u.z : (unsigned short)0;
            p.w = (c + 3 < 103) ? u.w : (unsigned short)0;
            ((ushort4*)pad)[t] = p;
        }
        if (sc) {
            float m = fmaxf(fmaxf(fabsf(v.x), fabsf(v.y)), fmaxf(fabsf(v.z), fabsf(v.w)));
#pragma unroll
            for (int off = 32; off; off >>= 1) m = fmaxf(m, __shfl_xor(m, off, 64));
            if ((t & 63) == 0) red[t >> 6] = m;
            __syncthreads();
            if (t == 0) {
                m = fmaxf(fmaxf(red[0], red[1]), fmaxf(red[2], red[3]));
                *sc = fmaxf(m, 1e-5f) * (1.0f / 127.0f);
            }
        }
    } else {
        float m = 0.f;
        for (int k = t; k < 4096; k += 256) { m = fmaxf(m, fabsf(b1[k])); counts[k] = 0; }
#pragma unroll
        for (int off = 32; off; off >>= 1) m = fmaxf(m, __shfl_xor(m, off, 64));
        if ((t & 63) == 0) red[t >> 6] = m;
        __syncthreads();
        if (t == 0) {
            m = fmaxf(fmaxf(red[0], red[1]), fmaxf(red[2], red[3]));
            *s_b = fmaxf(m, 1e-5f) * (1.0f / 127.0f);
        }
    }
}

// --------------------------- gemm1 + topk (fused dispatch) -------------------
// z=0 (64x32 blocks): h = gelu(x.W1^T + b1), slab epilogue.
// z=1 (64x32 blocks): topk counts (K=128 on padded operands) — these blocks
// finish in 4 K-iters and free CU slots back to gemm1 blocks.
__global__ __launch_bounds__(256, 4)
void gemm1_topk(const unsigned short* __restrict__ xb,
                const unsigned short* __restrict__ w1b,
                const unsigned short* __restrict__ xpad,
                const unsigned short* __restrict__ w1pad,
                const float* __restrict__ b1,
                unsigned short* __restrict__ hbuf,
                int* __restrict__ counts)
{
    __shared__ unsigned short lds[8192];
    v4f acc[4][4];
    v4f z = {0.f, 0.f, 0.f, 0.f};
#pragma unroll
    for (int i = 0; i < 4; ++i)
#pragma unroll
        for (int j = 0; j < 4; ++j) acc[i][j] = z;

    const int bm0 = blockIdx.x * 128, bn0 = blockIdx.y * 128;
    const int tid = threadIdx.x;
    const int lane = tid & 63, wave = tid >> 6;
    const int wm = wave & 1, wn = wave >> 1, q = lane >> 4;

    if (blockIdx.z == 0) {
        gemm_core(xb, w1b, 1024, bm0, bn0, lds, acc);

        float bvj[4];
#pragma unroll
        for (int j = 0; j < 4; ++j) bvj[j] = b1[bn0 + wn * 64 + j * 16 + (lane & 15)];

#pragma unroll
        for (int p = 0; p < 2; ++p) {
            __syncthreads();
            if (wm == p) {
#pragma unroll
                for (int j = 0; j < 4; ++j) {
                    int nl = wn * 64 + j * 16 + (lane & 15);
#pragma unroll
                    for (int i = 0; i < 4; ++i)
#pragma unroll
                        for (int r = 0; r < 4; ++r)
                            lds[(i * 16 + q * 4 + r) * 128 + nl] =
                                f2bf(gelu_fast(acc[i][j][r] + bvj[j]));
                }
            }
            __syncthreads();
#pragma unroll
            for (int s = 0; s < 4; ++s) {
                int c = s * 256 + tid;
                int row = c >> 4, ch = c & 15;
                *(v8us*)&hbuf[(size_t)(bm0 + p * 64 + row) * 4096 + bn0 + ch * 8] =
                    *(const v8us*)&lds[row * 128 + ch * 8];
            }
        }
    } else {
        gemm_core(xpad, w1pad, 128, bm0, bn0, lds, acc);

#pragma unroll
        for (int j = 0; j < 4; ++j) {
            int n = bn0 + wn * 64 + j * 16 + (lane & 15);
            float bv = b1[n];
            int cnt = 0;
#pragma unroll
            for (int i = 0; i < 4; ++i)
#pragma unroll
                for (int r = 0; r < 4; ++r)
                    cnt += (acc[i][j][r] + bv > 0.0f) ? 1 : 0;
            cnt += __shfl_xor(cnt, 16, 64);
            cnt += __shfl_xor(cnt, 32, 64);
            if (lane < 16 && cnt) atomicAdd(&counts[n], cnt);
        }
    }
}

// --------------------------- fixup (exact quant path) ------------------------
__global__ void fixup_kernel(const float* __restrict__ x,
                             const float* __restrict__ W1,
                             const float* __restrict__ b1,
                             const int* __restrict__ counts,
                             const float* __restrict__ s_x,
                             const float* __restrict__ s_w,
                             const float* __restrict__ s_b,
                             unsigned short* __restrict__ hbuf)
{
    const int n = blockIdx.x;
    if (counts[n] > 2048) return;   // fp channel: keep gemm1 result
    __shared__ float qw[1024];
    const float swn = s_w[n];
    for (int k = threadIdx.x; k < 1024; k += 256) {
        float q = nearbyintf(W1[(size_t)n * 1024 + k] / swn);
        qw[k] = fminf(fmaxf(q, -128.f), 127.f) * swn;
    }
    __syncthreads();
    const float sb = *s_b;
    const float bq = fminf(fmaxf(nearbyintf(b1[n] / sb), -128.f), 127.f) * sb;
    for (int m = threadIdx.x; m < 8192; m += 256) {
        const float sxm = s_x[m];
        float a = 0.f;
        for (int k = 0; k < 1024; ++k) {
            float q = nearbyintf(x[(size_t)m * 1024 + k] / sxm);
            a += fminf(fmaxf(q, -128.f), 127.f) * sxm * qw[k];
        }
        hbuf[(size_t)m * 4096 + n] = f2bf(gelu_exact(a + bq));
    }
}

// --------------------------- gemm2 + bias (128x64 tile) ----------------------
// 1024 blocks -> 4 blocks/CU (R4: 512-block version was capped at 2/CU, 22%).
// Epilogue: 4 passes of a 32x64 fp32 LDS slab (8 KB), coalesced float4 out.
__global__ __launch_bounds__(256, 4)
void gemm2_bias(const unsigned short* __restrict__ hbuf,
                const unsigned short* __restrict__ w2b,
                const float* __restrict__ b2,
                float* __restrict__ out)
{
    __shared__ unsigned short lds[6144];   // 12 KB
    v4f acc[4][2];
    v4f z = {0.f, 0.f, 0.f, 0.f};
#pragma unroll
    for (int i = 0; i < 4; ++i)
#pragma unroll
        for (int j = 0; j < 2; ++j) acc[i][j] = z;

    const int bm0 = blockIdx.x * 128, bn0 = blockIdx.y * 64;
    gemm_core64N(hbuf, w2b, 4096, bm0, bn0, lds, acc);

    const int tid = threadIdx.x;
    const int lane = tid & 63, wave = tid >> 6;
    const int wm = wave & 1, wn = wave >> 1, q = lane >> 4;
    float* ldsf = (float*)lds;             // 32x64 slab = 8 KB

    float bvj[2];
#pragma unroll
    for (int j = 0; j < 2; ++j) bvj[j] = b2[bn0 + wn * 32 + j * 16 + (lane & 15)];

#pragma unroll
    for (int p = 0; p < 4; ++p) {
        __syncthreads();
        if (wm == (p >> 1)) {
            const int ibase = (p & 1) * 2;
#pragma unroll
            for (int ii = 0; ii < 2; ++ii) {
#pragma unroll
                for (int j = 0; j < 2; ++j) {
                    int nl = wn * 32 + j * 16 + (lane & 15);
#pragma unroll
                    for (int r = 0; r < 4; ++r)
                        ldsf[(ii * 16 + q * 4 + r) * 64 + nl] =
                            acc[ibase + ii][j][r] + bvj[j];
                }
            }
        }
        __syncthreads();
#pragma unroll
        for (int s = 0; s < 2; ++s) {
            int c = s * 256 + tid;           // 0..511
            int row = c >> 4, ch = c & 15;   // 32 rows x 16 chunks of 16B
            *(float4*)&out[(size_t)(bm0 + p * 32 + row) * 1024 + bn0 + ch * 4] =
                *(const float4*)&ldsf[row * 64 + ch * 4];
        }
    }
}

// --------------------------- launch ----------------------------------------
extern "C" void kernel_launch(void* const* d_in, const int* in_sizes, int n_in,
                              void* d_out, int out_size, void* d_ws, size_t ws_size,
                              hipStream_t stream)
{
    const float* x  = (const float*)d_in[0];   // [4,2048,1024] fp32
    const float* W1 = (const float*)d_in[1];   // [4096,1024]
    const float* b1 = (const float*)d_in[2];   // [4096]
    const float* W2 = (const float*)d_in[3];   // [1024,4096]
    const float* b2 = (const float*)d_in[4];   // [1024]
    float* out = (float*)d_out;                // [4,2048,1024] fp32 (32 MB)

    // bf16 copies of x and W1 parked in d_out (dead until gemm2 writes it):
    unsigned short* xb  = (unsigned short*)d_out;                       // 16 MB
    unsigned short* w1b = (unsigned short*)d_out + (size_t)8192 * 1024; // 8 MB

    char* ws = (char*)d_ws;
    int*   counts = (int*)(ws + 0);                       // 16 KB
    float* s_x    = (float*)(ws + (64 << 10));            // 32 KB
    float* s_w    = (float*)(ws + (96 << 10));            // 16 KB
    float* s_b    = (float*)(ws + (112 << 10));           // 4 B
    unsigned short* xpad  = (unsigned short*)(ws + (1 << 20));   // 2 MB
    unsigned short* w1pad = (unsigned short*)(ws + (3 << 20));   // 1 MB
    unsigned short* w2b   = (unsigned short*)(ws + (4 << 20));   // 8 MB
    unsigned short* hbuf  = (unsigned short*)(ws + (12 << 20));  // 64 MB -> 76 MB total

    prep_kernel<<<16385, 256, 0, stream>>>(x, W1, W2, b1, xb, w1b, w2b,
                                           xpad, w1pad, s_x, s_w, s_b, counts);
    gemm1_topk<<<dim3(64, 32, 2), 256, 0, stream>>>(xb, w1b, xpad, w1pad, b1, hbuf, counts);
    fixup_kernel<<<4096, 256, 0, stream>>>(x, W1, b1, counts, s_x, s_w, s_b, hbuf);
    gemm2_bias<<<dim3(64, 16), 256, 0, stream>>>(hbuf, w2b, b2, out);
}